// Round 2
// 470.495 us; speedup vs baseline: 1.0012x; 1.0012x over previous
//
#include <hip/hip_runtime.h>
#include <math.h>

#define NH 512
#define BATCH 256
#define TT 512
#define NSTEPS 511           // recurrence steps (t = 0..510 produce states 1..511)
#define ALPHA 0.2f
#define OMA 0.8f
// sqrt(2/0.2 * 0.2^2) = sqrt(0.4)
#define ISCALE 0.6324555320336759f
#define PD 12                // noise prefetch depth (steps in flight per wave)
#define WPB 4                // waves per batch: each wave owns 128 hidden units

typedef float vf2 __attribute__((ext_vector_type(2)));
typedef float vf4 __attribute__((ext_vector_type(4)));

// ---------------- helpers ----------------

__device__ __forceinline__ float wave_reduce_sum(float v) {
#pragma unroll
    for (int m = 32; m >= 1; m >>= 1) v += __shfl_xor(v, m, 64);
    return v;
}

__device__ __forceinline__ unsigned long long enc_key(float v, int i) {
    // v >= 0: float bits are order-preserving
    return (((unsigned long long)__float_as_uint(v)) << 32) | (unsigned int)i;
}

__device__ __forceinline__ unsigned long long wave_max_key(unsigned long long k) {
#pragma unroll
    for (int m = 32; m >= 1; m >>= 1) {
        unsigned long long o = __shfl_xor(k, m, 64);
        k = (o > k) ? o : k;
    }
    return k;
}

// argmax index over rn[0..511], computed redundantly per wave (deterministic)
__device__ __forceinline__ int scan_argmax_rn(const float* __restrict__ rn, int tid) {
    const float4* rn4 = (const float4*)rn;
    unsigned long long key = 0;
#pragma unroll
    for (int r = 0; r < 2; ++r) {
        float4 v = rn4[tid + 64 * r];
        int base = 4 * (tid + 64 * r);
        unsigned long long k0 = enc_key(v.x, base);
        unsigned long long k1 = enc_key(v.y, base + 1);
        unsigned long long k2 = enc_key(v.z, base + 2);
        unsigned long long k3 = enc_key(v.w, base + 3);
        k0 = k0 > k1 ? k0 : k1;
        k2 = k2 > k3 ? k2 : k3;
        k0 = k0 > k2 ? k0 : k2;
        key = key > k0 ? key : k0;
    }
    return (int)(wave_max_key(key) & 0xffffffffULL);
}

// full-wave sum via DPP (VALU pipe, no LDS): result valid in lane 63
__device__ __forceinline__ float dpp_sum63(float v) {
    v += __int_as_float(__builtin_amdgcn_update_dpp(0, __float_as_int(v), 0x111, 0xf, 0xf, true)); // row_shr:1
    v += __int_as_float(__builtin_amdgcn_update_dpp(0, __float_as_int(v), 0x112, 0xf, 0xf, true)); // row_shr:2
    v += __int_as_float(__builtin_amdgcn_update_dpp(0, __float_as_int(v), 0x114, 0xf, 0xf, true)); // row_shr:4
    v += __int_as_float(__builtin_amdgcn_update_dpp(0, __float_as_int(v), 0x118, 0xf, 0xf, true)); // row_shr:8
    v += __int_as_float(__builtin_amdgcn_update_dpp(0, __float_as_int(v), 0x142, 0xa, 0xf, true)); // row_bcast15
    v += __int_as_float(__builtin_amdgcn_update_dpp(0, __float_as_int(v), 0x143, 0xc, 0xf, true)); // row_bcast31
    return v;
}

// ---------------- setup: rank-2 factorization of W_rec ----------------
// ws layout: idx @0 (2 ints), rn @64 (512 f), dv @2112 (512 f), P @4160 (1024 f)

__global__ void k_rownorm(const float* __restrict__ W, float* __restrict__ rn) {
    const int i = blockIdx.x, tid = threadIdx.x;
    const float4* row = (const float4*)(W + (size_t)i * NH);
    float acc = 0.f;
#pragma unroll
    for (int r = 0; r < 2; ++r) {
        float4 v = row[tid + 64 * r];
        acc = fmaf(v.x, v.x, fmaf(v.y, v.y, fmaf(v.z, v.z, fmaf(v.w, v.w, acc))));
    }
    acc = wave_reduce_sum(acc);
    if (tid == 0) rn[i] = acc;
}

__global__ void k_rowdot(const float* __restrict__ W, const float* __restrict__ rn,
                         float* __restrict__ dv) {
    const int i = blockIdx.x, tid = threadIdx.x;
    const int i1 = scan_argmax_rn(rn, tid);
    const float4* rowi = (const float4*)(W + (size_t)i * NH);
    const float4* row1 = (const float4*)(W + (size_t)i1 * NH);
    float acc = 0.f;
#pragma unroll
    for (int r = 0; r < 2; ++r) {
        float4 a = rowi[tid + 64 * r];
        float4 b = row1[tid + 64 * r];
        acc = fmaf(a.x, b.x, fmaf(a.y, b.y, fmaf(a.z, b.z, fmaf(a.w, b.w, acc))));
    }
    acc = wave_reduce_sum(acc);
    if (tid == 0) dv[i] = acc;
}

// Least-squares P[n,0:2] (pre-scaled by ALPHA): W[n,:] ~= c0*W[i1,:] + c1*W[i2,:]
__global__ void k_computeP(const float* __restrict__ W, const float* __restrict__ rn,
                           const float* __restrict__ dv, float* __restrict__ P,
                           int* __restrict__ idx) {
    const int n = blockIdx.x, tid = threadIdx.x;
    const int i1 = scan_argmax_rn(rn, tid);
    const float rn1 = rn[i1];
    const float inv1 = 1.f / rn1;

    // residual argmax -> i2 (exclude i1)
    const float4* rn4 = (const float4*)rn;
    const float4* dv4 = (const float4*)dv;
    unsigned long long key = 0;
#pragma unroll
    for (int r = 0; r < 2; ++r) {
        float4 a = rn4[tid + 64 * r];
        float4 d = dv4[tid + 64 * r];
        int base = 4 * (tid + 64 * r);
        float r0 = fmaxf(a.x - d.x * d.x * inv1, 0.f);
        float r1 = fmaxf(a.y - d.y * d.y * inv1, 0.f);
        float r2 = fmaxf(a.z - d.z * d.z * inv1, 0.f);
        float r3 = fmaxf(a.w - d.w * d.w * inv1, 0.f);
        unsigned long long k0 = (base + 0 != i1) ? enc_key(r0, base + 0) : 0ULL;
        unsigned long long k1 = (base + 1 != i1) ? enc_key(r1, base + 1) : 0ULL;
        unsigned long long k2 = (base + 2 != i1) ? enc_key(r2, base + 2) : 0ULL;
        unsigned long long k3 = (base + 3 != i1) ? enc_key(r3, base + 3) : 0ULL;
        k0 = k0 > k1 ? k0 : k1;
        k2 = k2 > k3 ? k2 : k3;
        k0 = k0 > k2 ? k0 : k2;
        key = key > k0 ? key : k0;
    }
    const int i2 = (int)(wave_max_key(key) & 0xffffffffULL);

    const float4* rown = (const float4*)(W + (size_t)n * NH);
    const float4* row1 = (const float4*)(W + (size_t)i1 * NH);
    const float4* row2 = (const float4*)(W + (size_t)i2 * NH);
    float t0 = 0.f, t1 = 0.f;
#pragma unroll
    for (int r = 0; r < 2; ++r) {
        float4 a = rown[tid + 64 * r];
        float4 b = row1[tid + 64 * r];
        float4 c = row2[tid + 64 * r];
        t0 = fmaf(a.x, b.x, fmaf(a.y, b.y, fmaf(a.z, b.z, fmaf(a.w, b.w, t0))));
        t1 = fmaf(a.x, c.x, fmaf(a.y, c.y, fmaf(a.z, c.z, fmaf(a.w, c.w, t1))));
    }
    t0 = wave_reduce_sum(t0);
    t1 = wave_reduce_sum(t1);
    if (tid == 0) {
        float g11 = rn1, g22 = rn[i2], g12 = dv[i2];
        float det = fmaf(g11, g22, -g12 * g12);
        float inv = 1.f / det;
        P[2 * n]     = ALPHA * ((g22 * t0 - g12 * t1) * inv);
        P[2 * n + 1] = ALPHA * ((g11 * t1 - g12 * t0) * inv);
        if (n == 0) { idx[0] = i1; idx[1] = i2; }
    }
}

// ---------------- main recurrence ----------------
// 4 waves per batch (block = 256 threads); each wave owns 128 hidden units,
// each lane 2. The rank-2 coupling means waves exchange only 2 scalar
// partials per step via a 32 B double-buffered LDS slot + ONE barrier/step.
//
// Barrier-ordering safety of the single barrier + 2 buffers:
//   wave w: ... read(t) [after bar(t)] ... write(t+1), bar(t+1), read(t+1) ...
//   any wave v's write(t+2) (same slot as read(t)) comes after v passed
//   bar(t+1), and every wave passes bar(t+1) only after its read(t). QED.
//
// Rationale vs the previous 1-wave/batch version: one wave sustains only
// ~5 B/cyc of HBM streaming (m13: peak BW needs 8 waves/CU), which capped
// the old kernel at 818 cyc/step. 4 waves/CU cuts per-wave traffic 4x;
// the serial chain (fmax->mul->fma->6 DPP->LDS xchg->2 FMA) is ~250 cyc,
// under the ~400 cyc memory-side step time.
__launch_bounds__(256, 1)
__global__ void k_main(const float* __restrict__ u, const float* __restrict__ inoise,
                       const float* __restrict__ rnoise, const float* __restrict__ W_in,
                       const float* __restrict__ W, const float* __restrict__ b_rec,
                       const int* __restrict__ idx, const float* __restrict__ P,
                       float* __restrict__ out) {
    __shared__ __align__(16) float2 lds_x[TT];      // x[t,0:2] = u + ISCALE*input_noise
    __shared__ __align__(16) float2 lds_p[2][WPB];  // per-wave (p0,p1) partials, dbuf
    const int b = blockIdx.x;
    const int tid = threadIdx.x;        // 0..255
    const int wid = tid >> 6;
    const int lane = tid & 63;
    const int i1 = idx[0];
    const int i2 = idx[1];

    // stage x: 1024 floats = 256 float4, one per thread
    {
        const float4* u4 = (const float4*)(u + (size_t)b * TT * 2);
        const float4* n4 = (const float4*)(inoise + (size_t)b * TT * 2);
        float4 a = u4[tid];
        float4 c = n4[tid];
        float4 x;
        x.x = fmaf(ISCALE, c.x, a.x);
        x.y = fmaf(ISCALE, c.y, a.y);
        x.z = fmaf(ISCALE, c.z, a.z);
        x.w = fmaf(ISCALE, c.w, a.w);
        ((float4*)lds_x)[tid] = x;
    }
    __syncthreads();

    // this lane's two hidden units
    const int n0 = (wid << 7) + (lane << 1);
    const float q0x = W[(size_t)i1 * NH + n0],     q0y = W[(size_t)i1 * NH + n0 + 1];
    const float q1x = W[(size_t)i2 * NH + n0],     q1y = W[(size_t)i2 * NH + n0 + 1];
    const float A0x = P[2 * n0],                   A1x = P[2 * n0 + 1];
    const float A0y = P[2 * n0 + 2],               A1y = P[2 * n0 + 3];
    const float w0x = ALPHA * W_in[2 * n0],        w1x = ALPHA * W_in[2 * n0 + 1];
    const float w0y = ALPHA * W_in[2 * n0 + 2],    w1y = ALPHA * W_in[2 * n0 + 3];
    const float cbx = ALPHA * b_rec[n0],           cby = ALPHA * b_rec[n0 + 1];
    float sx = 0.f, sy = 0.f;

    const float* nzb = rnoise + (size_t)b * TT * NH + n0;
    float* ob = out + (size_t)b * TT * NH + n0;

    // states[:,0,:] = 0
    vf2 z = {0.f, 0.f};
    __builtin_nontemporal_store(z, (vf2*)ob);

    // noise prefetch: PD steps in flight, 8 B/lane each (dwordx2, coalesced)
    vf2 buf[PD];
#pragma unroll
    for (int k = 0; k < PD; ++k) buf[k] = *(const vf2*)(nzb + (size_t)k * NH);

#define STEP(t_, k_, REFILL_, XX_, XY_)                                              \
    {                                                                                \
        const int t = (t_);                                                          \
        vf2 nz = buf[k_];                                                            \
        if (REFILL_) {                                                               \
            int tp = t + PD; if (tp > NSTEPS) tp = NSTEPS; /* row 511 is valid */    \
            buf[k_] = *(const vf2*)(nzb + (size_t)tp * NH);                          \
        }                                                                            \
        const float xx = (XX_);                                                      \
        const float xy = (XY_);                                                      \
        float rsx = fmaxf(sx, 0.f), rsy = fmaxf(sy, 0.f);                            \
        float pa = fmaf(rsy, q0y, rsx * q0x);                                        \
        float pb = fmaf(rsy, q1y, rsx * q1x);                                        \
        pa = dpp_sum63(pa);                                                          \
        pb = dpp_sum63(pb);                                                          \
        /* base terms are off the p-chain: computed under barrier/LDS latency */     \
        float bx = fmaf(ALPHA, nz.x, cbx);                                           \
        bx = fmaf(w0x, xx, bx);                                                      \
        bx = fmaf(w1x, xy, bx);                                                      \
        bx = fmaf(OMA, sx, bx);                                                      \
        float by = fmaf(ALPHA, nz.y, cby);                                           \
        by = fmaf(w0y, xx, by);                                                      \
        by = fmaf(w1y, xy, by);                                                      \
        by = fmaf(OMA, sy, by);                                                      \
        if (lane == 63) lds_p[(t) & 1][wid] = make_float2(pa, pb);                   \
        __syncthreads();                                                             \
        const float4* pp = (const float4*)lds_p[(t) & 1];                            \
        float4 r0 = pp[0];                                                           \
        float4 r1 = pp[1];                                                           \
        float p0 = (r0.x + r0.z) + (r1.x + r1.z);                                    \
        float p1 = (r0.y + r0.w) + (r1.y + r1.w);                                    \
        sx = fmaf(A1x, p1, fmaf(A0x, p0, bx));                                       \
        sy = fmaf(A1y, p1, fmaf(A0y, p0, by));                                       \
        vf2 o = {sx, sy};                                                            \
        __builtin_nontemporal_store(o, (vf2*)(ob + (size_t)(t + 1) * NH));           \
    }

    // 511 = 42*12 + 7: full blocks cover t in [0,504), tail covers [504,511)
    for (int tb = 0; tb < 504; tb += PD) {
        // hoist this block's 12 wave-uniform x reads (6 x ds_read_b128)
        const float4* lxs = (const float4*)(lds_x + tb);
        float4 xb[6];
#pragma unroll
        for (int r = 0; r < 6; ++r) xb[r] = lxs[r];
#pragma unroll
        for (int k = 0; k < PD; ++k) {
            STEP(tb + k, k, true,
                 ((k & 1) ? xb[k >> 1].z : xb[k >> 1].x),
                 ((k & 1) ? xb[k >> 1].w : xb[k >> 1].y))
        }
    }
    {
        const float4* lxs = (const float4*)(lds_x + 504);
        float4 xb[4];
#pragma unroll
        for (int r = 0; r < 4; ++r) xb[r] = lxs[r];
#pragma unroll
        for (int k = 0; k < 7; ++k) {
            STEP(504 + k, k, false,
                 ((k & 1) ? xb[k >> 1].z : xb[k >> 1].x),
                 ((k & 1) ? xb[k >> 1].w : xb[k >> 1].y))
        }
    }

#undef STEP
}

// ---------------- launch ----------------

extern "C" void kernel_launch(void* const* d_in, const int* in_sizes, int n_in,
                              void* d_out, int out_size, void* d_ws, size_t ws_size,
                              hipStream_t stream) {
    const float* u      = (const float*)d_in[0];
    const float* inoise = (const float*)d_in[1];
    const float* rnoise = (const float*)d_in[2];
    const float* W_in   = (const float*)d_in[3];
    const float* W      = (const float*)d_in[4];
    const float* b_rec  = (const float*)d_in[5];
    float* out = (float*)d_out;

    char* ws = (char*)d_ws;
    int* idx  = (int*)(ws + 0);
    float* rn = (float*)(ws + 64);
    float* dv = (float*)(ws + 2112);
    float* P  = (float*)(ws + 4160);

    hipLaunchKernelGGL(k_rownorm, dim3(NH), dim3(64), 0, stream, W, rn);
    hipLaunchKernelGGL(k_rowdot, dim3(NH), dim3(64), 0, stream, W, rn, dv);
    hipLaunchKernelGGL(k_computeP, dim3(NH), dim3(64), 0, stream, W, rn, dv, P, idx);
    hipLaunchKernelGGL(k_main, dim3(BATCH), dim3(256), 0, stream,
                       u, inoise, rnoise, W_in, W, b_rec, idx, P, out);
}